// Round 6
// baseline (708.050 us; speedup 1.0000x reference)
//
#include <hip/hip_runtime.h>
#include <math.h>

#define NNODES 100000
#define NSUB   65536
#define NEDGE  655360
#define NBATCH 4096
#define LDK 72   // LDS k-stride (elements): 144B rows -> 2-way-only bank conflicts (free)

typedef __attribute__((ext_vector_type(8))) short short8;
typedef __attribute__((ext_vector_type(4))) float f32x4;

__device__ __forceinline__ unsigned short f2bf(float x) {
  unsigned int b = __float_as_uint(x);
  b += 0x7fffu + ((b >> 16) & 1u);           // RNE
  return (unsigned short)(b >> 16);
}
__device__ __forceinline__ float bflo(unsigned int u) { return __uint_as_float(u << 16); }
__device__ __forceinline__ float bfhi(unsigned int u) { return __uint_as_float(u & 0xffff0000u); }
__device__ __forceinline__ unsigned int pk2(float a, float b) {
  return (unsigned int)f2bf(a) | ((unsigned int)f2bf(b) << 16);
}
__device__ __forceinline__ void unpack8(uint4 u, float* a, float* b) {
  a[0] = bflo(u.x); b[0] = bfhi(u.x);
  a[1] = bflo(u.y); b[1] = bfhi(u.y);
  a[2] = bflo(u.z); b[2] = bfhi(u.z);
  a[3] = bflo(u.w); b[3] = bfhi(u.w);
}
__device__ __forceinline__ ushort4 pkv4(float a, float b, float c, float d) {
  return make_ushort4(f2bf(a), f2bf(b), f2bf(c), f2bf(d));
}

__global__ void k_sentinel(float* out) { out[0] = -12345.0f; }

// ---- merged weight packing (packW | packW2 | bem by block range) ----------
// Wt[768][256] bf16, n-major. Column layout (== nodeout row layout):
// [0:128) q ilv (2l+h) *1/8
// [128:384) kv-interleaved blocks: for j in [0,16): 8 k-elems (i=8j+r, l=i>>1,
//           h=i&1) then 8 v-elems — lane j's k and v are 32B contiguous
// [384:512) skip | [512:640) qWe-cos ilv *1/8 | [640:768) qWe-msg ilv *1/8
__global__ void k_packAll(const float* __restrict__ Wq, const float* __restrict__ bq,
                          const float* __restrict__ Wk, const float* __restrict__ bk,
                          const float* __restrict__ Wv, const float* __restrict__ bv,
                          const float* __restrict__ Ws, const float* __restrict__ bs,
                          const float* __restrict__ We, const float* __restrict__ mlp_w,
                          const float* __restrict__ be,
                          unsigned short* __restrict__ Wt, float* __restrict__ bias,
                          unsigned short* __restrict__ W2t, float* __restrict__ bem) {
  int b = blockIdx.x, t = threadIdx.x;
  if (b < 768) {
    int n = b, r = t;
    float v = 0.f, bn = 0.f;
    if (n < 128) {
      int l = n >> 1, h = n & 1;
      v = Wq[r * 128 + h * 64 + l] * 0.125f; bn = bq[h * 64 + l] * 0.125f;
    } else if (n < 384) {
      int p = n - 128, jj = p >> 4, r2 = p & 15;
      if (r2 < 8) { int i = jj * 8 + r2; int l = i >> 1, h = i & 1;
        v = Wk[r * 128 + h * 64 + l]; bn = bk[h * 64 + l]; }
      else { int i = jj * 8 + (r2 - 8); int l = i >> 1, h = i & 1;
        v = Wv[r * 128 + h * 64 + l]; bn = bv[h * 64 + l]; }
    } else if (n < 512) {
      int c = n - 384; v = Ws[r * 128 + c]; bn = bs[c];
    } else {
      int i = (n < 640) ? (n - 512) : (n - 640);
      int c = i >> 1, h = i & 1;
      int kk = (n < 640) ? c : (64 + c);
      float s = 0.f;
      for (int d = 0; d < 64; d++) s += Wq[r * 128 + h * 64 + d] * We[kk * 128 + h * 64 + d];
      v = s * 0.125f;
      if (r == 0) {
        float sb = 0.f;
        for (int d = 0; d < 64; d++) sb += bq[h * 64 + d] * We[kk * 128 + h * 64 + d];
        bn = sb * 0.125f;
      }
    }
    Wt[(size_t)n * 256 + r] = f2bf(v);
    if (r == 0) bias[n] = bn;
  } else if (b < 896) {
    // W2t[64][512]: cols of A2 = [aggV(128)|cos0 msg0 cos1 msg1(256)|skip(128)]
    int r = (b - 768) * 4 + (t >> 6), j = t & 63;
    float v;
    if (r < 128) v = mlp_w[r * 64 + j];
    else if (r < 192) { int k = r - 128; float s = 0; for (int c = 0; c < 64; c++) s += We[k * 128 + c] * mlp_w[c * 64 + j]; v = s; }
    else if (r < 256) { int k = r - 192; float s = 0; for (int c = 0; c < 64; c++) s += We[(64 + k) * 128 + c] * mlp_w[c * 64 + j]; v = s; }
    else if (r < 320) { int k = r - 256; float s = 0; for (int c = 0; c < 64; c++) s += We[k * 128 + 64 + c] * mlp_w[(64 + c) * 64 + j]; v = s; }
    else if (r < 384) { int k = r - 320; float s = 0; for (int c = 0; c < 64; c++) s += We[(64 + k) * 128 + 64 + c] * mlp_w[(64 + c) * 64 + j]; v = s; }
    else v = mlp_w[(r - 384) * 64 + j];
    W2t[(size_t)j * 512 + r] = f2bf(v);
  } else {
    if (t < 64) {
      int h = b - 896, j = t;
      float s = 0.f;
      for (int c = 0; c < 64; c++) s += be[h * 64 + c] * mlp_w[(h * 64 + c) * 64 + j];
      bem[h * 64 + j] = s;
    }
  }
}

// ---- prep: anodes bf16 gather + assoc -------------------------------------
__global__ void k_packA(const float* __restrict__ mem, const float* __restrict__ pmem,
                        const int* __restrict__ n_id, unsigned short* __restrict__ anodes,
                        int* __restrict__ assoc) {
  int i = blockIdx.x * 256 + threadIdx.x;   // 8-elem chunk index
  if (i < NSUB) assoc[n_id[i]] = i;
  int node = i >> 5, ch = i & 31;
  int nid = n_id[node];
  const float* src = (ch < 16) ? (mem + (size_t)nid * 128 + ch * 8)
                               : (pmem + (size_t)nid * 128 + (ch - 16) * 8);
  float4 f0 = *(const float4*)src, f1 = *(const float4*)(src + 4);
  uint4 o;
  o.x = pk2(f0.x, f0.y); o.y = pk2(f0.z, f0.w);
  o.z = pk2(f1.x, f1.y); o.w = pk2(f1.z, f1.w);
  *(uint4*)(anodes + (size_t)node * 256 + ch * 8) = o;
}

// ---- msg bf16 convert + rel_t + deg (fused) -------------------------------
__global__ void k_msgb(const float* __restrict__ edge_msg, unsigned int* __restrict__ msgb,
                       const int* __restrict__ edge_index, const int* __restrict__ n_id,
                       const float* __restrict__ last_update, const float* __restrict__ edge_t,
                       float* __restrict__ rel_t, int* __restrict__ deg) {
  int i = blockIdx.x * 256 + threadIdx.x;   // i < NEDGE*32
  float2 f = *(const float2*)(edge_msg + (size_t)i * 2);
  msgb[i] = pk2(f.x, f.y);
  if (i < NEDGE) {
    rel_t[i] = last_update[n_id[edge_index[i]]] - edge_t[i];
    atomicAdd(&deg[edge_index[NEDGE + i]], 1);
  }
}

// ---- 2-phase scan (scan2 folded into scan3) -------------------------------
__global__ __launch_bounds__(1024)
void k_scan1(const int* __restrict__ deg, int* __restrict__ excl, int* __restrict__ btot) {
  __shared__ int wsum[16];
  int t = threadIdx.x, w = t >> 6, l = t & 63;
  int i = blockIdx.x * 1024 + t;
  int v = deg[i], s = v;
  #pragma unroll
  for (int d = 1; d < 64; d <<= 1) { int u = __shfl_up(s, d, 64); if (l >= d) s += u; }
  if (l == 63) wsum[w] = s;
  __syncthreads();
  int woff = 0;
  #pragma unroll
  for (int k = 0; k < 16; k++) woff += (k < w) ? wsum[k] : 0;
  excl[i] = woff + s - v;
  if (t == 1023) btot[blockIdx.x] = woff + s;
}

__global__ __launch_bounds__(1024)
void k_scan3(const int* __restrict__ excl, const int* __restrict__ btot,
             int* __restrict__ offs, int* __restrict__ cursor) {
  int t = threadIdx.x, l = t & 63;
  int bid = blockIdx.x;                       // 64 blocks; each wave re-scans btot[64]
  int v = btot[l], s = v;
  #pragma unroll
  for (int d = 1; d < 64; d <<= 1) { int u = __shfl_up(s, d, 64); if (l >= d) s += u; }
  int boff = __shfl(s, bid, 64) - __shfl(v, bid, 64);
  int i = bid * 1024 + t;
  int o = excl[i] + boff;
  offs[i] = o; cursor[i] = o;
  if (bid == 63 && t == 1023) { offs[NSUB] = s; cursor[NSUB] = s; }   // s@lane63 = total
}

// csrmeta[p] = {se, rel_t bits, eid, 0} in CSR (dst-grouped) order
__global__ void k_scatter(const int* __restrict__ edge_index, const float* __restrict__ rel_t,
                          int* __restrict__ cursor, uint4* __restrict__ csrmeta) {
  int e = blockIdx.x * 256 + threadIdx.x;
  if (e < NEDGE) {
    int de = edge_index[NEDGE + e];
    int p = atomicAdd(&cursor[de], 1);
    csrmeta[p] = make_uint4((unsigned)edge_index[e], __float_as_uint(rel_t[e]), (unsigned)e, 0u);
  }
}

// ---- node GEMM: [65536,256] @ [256,768], 256x128 tile, 8x4 acc/wave -------
__global__ __launch_bounds__(256)
void k_gemm_node(const unsigned short* __restrict__ anodes, const unsigned short* __restrict__ Wt,
                 const float* __restrict__ bias, unsigned short* __restrict__ nodeout) {
  __shared__ unsigned short sA[256][LDK];
  __shared__ unsigned short sB[128][LDK];
  int t = threadIdx.x;
  int row0 = blockIdx.x * 256, n0 = blockIdx.y * 128;
  int ar = t >> 1, ak = (t & 1) * 32;
  int w = t >> 6, lane = t & 63, quad = lane >> 4, r16 = lane & 15;
  int m_off = (w >> 1) * 128, n_off = (w & 1) * 64;
  f32x4 acc[8][4] = {};
  for (int st = 0; st < 4; st++) {
    int ks = st * 64;
    __syncthreads();
    #pragma unroll
    for (int i = 0; i < 4; i++) {
      *(uint4*)&sA[ar][ak + i * 8]       = *(const uint4*)(anodes + (size_t)(row0 + ar) * 256 + ks + ak + i * 8);
      *(uint4*)&sA[ar + 128][ak + i * 8] = *(const uint4*)(anodes + (size_t)(row0 + ar + 128) * 256 + ks + ak + i * 8);
      *(uint4*)&sB[ar][ak + i * 8]       = *(const uint4*)(Wt + (size_t)(n0 + ar) * 256 + ks + ak + i * 8);
    }
    __syncthreads();
    #pragma unroll
    for (int kk = 0; kk < 2; kk++) {
      short8 af[8], bf_[4];
      #pragma unroll
      for (int i = 0; i < 8; i++) af[i]  = *(const short8*)&sA[m_off + i * 16 + r16][kk * 32 + quad * 8];
      #pragma unroll
      for (int i = 0; i < 4; i++) bf_[i] = *(const short8*)&sB[n_off + i * 16 + r16][kk * 32 + quad * 8];
      #pragma unroll
      for (int i = 0; i < 8; i++)
        #pragma unroll
        for (int j = 0; j < 4; j++)
          acc[i][j] = __builtin_amdgcn_mfma_f32_16x16x32_bf16(af[i], bf_[j], acc[i][j], 0, 0, 0);
    }
  }
  #pragma unroll
  for (int j = 0; j < 4; j++) {
    int col = n0 + n_off + j * 16 + r16;
    float bv_ = bias[col];
    #pragma unroll
    for (int i = 0; i < 8; i++) {
      int rbase = row0 + m_off + i * 16 + quad * 4;
      #pragma unroll
      for (int rg = 0; rg < 4; rg++)
        nodeout[(size_t)(rbase + rg) * 768 + col] = f2bf(acc[i][j][rg] + bv_);
    }
  }
}

// ---- fused edge pass: 16-lane group per dest node, chunk-16 meta prefetch -
__global__ __launch_bounds__(256)
void k_edge(const unsigned short* __restrict__ nodeout, const unsigned short* __restrict__ msgb,
            const float* __restrict__ time_w, const float* __restrict__ time_b,
            const float* __restrict__ be, const int* __restrict__ offs,
            const uint4* __restrict__ csrmeta, unsigned short* __restrict__ aggbuf,
            float* __restrict__ salph) {
  int t = threadIdx.x, w = t >> 6, lane = t & 63;
  int j = lane & 15;
  int node = blockIdx.x * 16 + w * 4 + (lane >> 4);
  const unsigned short* nr = nodeout + (size_t)node * 768;
  uint4 q4  = *(const uint4*)(nr + 8 * j);
  uint4 qc4 = *(const uint4*)(nr + 512 + 8 * j);
  uint4 qm4 = *(const uint4*)(nr + 640 + 8 * j);
  float4 tw4 = *(const float4*)(time_w + 4 * j);
  float4 tb4 = *(const float4*)(time_b + 4 * j);
  float4 beA = *(const float4*)(be + 4 * j);
  float4 beB = *(const float4*)(be + 64 + 4 * j);
  float q0[4], q1[4], qc0[4], qc1[4], qm0[4], qm1[4];
  unpack8(q4, q0, q1); unpack8(qc4, qc0, qc1); unpack8(qm4, qm0, qm1);
  float qbe0 = q0[0] * beA.x + q0[1] * beA.y + q0[2] * beA.z + q0[3] * beA.w;
  float qbe1 = q1[0] * beB.x + q1[1] * beB.y + q1[2] * beB.z + q1[3] * beB.w;
  #pragma unroll
  for (int s = 1; s < 16; s <<= 1) { qbe0 += __shfl_xor(qbe0, s, 64); qbe1 += __shfl_xor(qbe1, s, 64); }
  float d0 = 0.f, d1 = 0.f;
  float aV0[4] = {}, aV1[4] = {}, aC0[4] = {}, aC1[4] = {}, aM0[4] = {}, aM1[4] = {};
  int e0 = offs[node], e1 = offs[node + 1];
  int deg = e1 - e0;
  int lb = lane & 48;
  for (int base = 0; base < deg; base += 16) {
    int cidx = e0 + base + j;
    int hi = e1 - 1;
    cidx = cidx > hi ? hi : cidx;
    uint4 mt = csrmeta[cidx];                  // one coalesced 256B meta load / group
    int rem = deg - base; rem = rem > 16 ? 16 : rem;
    for (int c = 0; c < rem; c += 4) {
      uint4 kvr[4], vvr[4];
      uint2 mgr[4];
      float rtv[4];
      #pragma unroll
      for (int ii = 0; ii < 4; ii++) {
        int sl = lb | (c + ii);
        int se_i = __shfl((int)mt.x, sl, 64);
        rtv[ii] = __uint_as_float((unsigned)__shfl((int)mt.y, sl, 64));
        int eid_i = __shfl((int)mt.z, sl, 64);
        const unsigned short* ns = nodeout + (size_t)se_i * 768;
        kvr[ii] = *(const uint4*)(ns + 128 + 16 * j);       // k,v 32B contiguous
        vvr[ii] = *(const uint4*)(ns + 128 + 16 * j + 8);
        mgr[ii] = *(const uint2*)(msgb + (size_t)eid_i * 64 + 4 * j);
      }
      #pragma unroll
      for (int ii = 0; ii < 4; ii++) {
        float msk = (c + ii < rem) ? 1.f : 0.f;
        float k0[4], k1[4], v0[4], v1[4];
        unpack8(kvr[ii], k0, k1); unpack8(vvr[ii], v0, v1);
        float mgc[4] = {bflo(mgr[ii].x), bfhi(mgr[ii].x), bflo(mgr[ii].y), bfhi(mgr[ii].y)};
        float rt = rtv[ii];
        float cv[4];
        cv[0] = __cosf(rt * tw4.x + tb4.x);
        cv[1] = __cosf(rt * tw4.y + tb4.y);
        cv[2] = __cosf(rt * tw4.z + tb4.z);
        cv[3] = __cosf(rt * tw4.w + tb4.w);
        float p0 = q0[0] * k0[0] + q0[1] * k0[1] + q0[2] * k0[2] + q0[3] * k0[3]
                 + qc0[0] * cv[0] + qc0[1] * cv[1] + qc0[2] * cv[2] + qc0[3] * cv[3]
                 + qm0[0] * mgc[0] + qm0[1] * mgc[1] + qm0[2] * mgc[2] + qm0[3] * mgc[3];
        float p1 = q1[0] * k1[0] + q1[1] * k1[1] + q1[2] * k1[2] + q1[3] * k1[3]
                 + qc1[0] * cv[0] + qc1[1] * cv[1] + qc1[2] * cv[2] + qc1[3] * cv[3]
                 + qm1[0] * mgc[0] + qm1[1] * mgc[1] + qm1[2] * mgc[2] + qm1[3] * mgc[3];
        #pragma unroll
        for (int s = 1; s < 16; s <<= 1) { p0 += __shfl_xor(p0, s, 64); p1 += __shfl_xor(p1, s, 64); }
        float ex0 = __expf(p0 + qbe0) * msk, ex1 = __expf(p1 + qbe1) * msk;
        d0 += ex0; d1 += ex1;
        #pragma unroll
        for (int cc = 0; cc < 4; cc++) {
          aV0[cc] += ex0 * v0[cc]; aC0[cc] += ex0 * cv[cc]; aM0[cc] += ex0 * mgc[cc];
          aV1[cc] += ex1 * v1[cc]; aC1[cc] += ex1 * cv[cc]; aM1[cc] += ex1 * mgc[cc];
        }
      }
    }
  }
  float i0 = 1.f / (d0 + 1e-16f), i1 = 1.f / (d1 + 1e-16f);
  unsigned short* ag = aggbuf + (size_t)node * 512;
  *(ushort4*)(ag + 4 * j)       = pkv4(aV0[0] * i0, aV0[1] * i0, aV0[2] * i0, aV0[3] * i0);
  *(ushort4*)(ag + 64 + 4 * j)  = pkv4(aV1[0] * i1, aV1[1] * i1, aV1[2] * i1, aV1[3] * i1);
  *(ushort4*)(ag + 128 + 4 * j) = pkv4(aC0[0] * i0, aC0[1] * i0, aC0[2] * i0, aC0[3] * i0);
  *(ushort4*)(ag + 192 + 4 * j) = pkv4(aM0[0] * i0, aM0[1] * i0, aM0[2] * i0, aM0[3] * i0);
  *(ushort4*)(ag + 256 + 4 * j) = pkv4(aC1[0] * i1, aC1[1] * i1, aC1[2] * i1, aC1[3] * i1);
  *(ushort4*)(ag + 320 + 4 * j) = pkv4(aM1[0] * i1, aM1[1] * i1, aM1[2] * i1, aM1[3] * i1);
  *(uint4*)(ag + 384 + 8 * j)   = *(const uint4*)(nr + 384 + 8 * j);
  if (j == 0) { salph[node * 2] = d0 * i0; salph[node * 2 + 1] = d1 * i1; }
}

// ---- final GEMM: [65536,512] @ [512,64] bf16 MFMA -> h fp32 ---------------
__global__ __launch_bounds__(128)
void k_gemm_final(const unsigned short* __restrict__ aggbuf, const unsigned short* __restrict__ W2t,
                  const float* __restrict__ salph, const float* __restrict__ bem,
                  const float* __restrict__ mlp_b, float* __restrict__ h) {
  __shared__ unsigned short sA[128][LDK];
  __shared__ unsigned short sB[64][LDK];
  int t = threadIdx.x;
  int row0 = blockIdx.x * 128;
  int w = t >> 6, lane = t & 63, quad = lane >> 4, r16 = lane & 15;
  int m_off = w * 64;
  f32x4 acc[4][4] = {};
  for (int st = 0; st < 8; st++) {
    int ks = st * 64;
    __syncthreads();
    #pragma unroll
    for (int c = 0; c < 8; c++)
      *(uint4*)&sA[t][c * 8] = *(const uint4*)(aggbuf + (size_t)(row0 + t) * 512 + ks + c * 8);
    int brr = t >> 1;
    #pragma unroll
    for (int jj = 0; jj < 4; jj++) {
      int c = (t & 1) * 4 + jj;
      *(uint4*)&sB[brr][c * 8] = *(const uint4*)(W2t + (size_t)brr * 512 + ks + c * 8);
    }
    __syncthreads();
    #pragma unroll
    for (int kk = 0; kk < 2; kk++) {
      short8 af[4], bf_[4];
      #pragma unroll
      for (int i = 0; i < 4; i++) af[i]  = *(const short8*)&sA[m_off + i * 16 + r16][kk * 32 + quad * 8];
      #pragma unroll
      for (int i = 0; i < 4; i++) bf_[i] = *(const short8*)&sB[i * 16 + r16][kk * 32 + quad * 8];
      #pragma unroll
      for (int i = 0; i < 4; i++)
        #pragma unroll
        for (int jj = 0; jj < 4; jj++)
          acc[i][jj] = __builtin_amdgcn_mfma_f32_16x16x32_bf16(af[i], bf_[jj], acc[i][jj], 0, 0, 0);
    }
  }
  #pragma unroll
  for (int jj = 0; jj < 4; jj++) {
    int col = jj * 16 + r16;
    float mb = mlp_b[col], b0 = bem[col], b1 = bem[64 + col];
    #pragma unroll
    for (int i = 0; i < 4; i++) {
      int rbase = row0 + m_off + i * 16 + quad * 4;
      #pragma unroll
      for (int rg = 0; rg < 4; rg++) {
        int rr = rbase + rg;
        h[(size_t)rr * 64 + col] = acc[i][jj][rg] + mb + salph[rr * 2] * b0 + salph[rr * 2 + 1] * b1;
      }
    }
  }
}

__global__ __launch_bounds__(256)
void k_linkpred(const float* __restrict__ h, const int* __restrict__ assoc,
                const int* __restrict__ src, const int* __restrict__ dst,
                const int* __restrict__ neg, const float* __restrict__ lps_w,
                const float* __restrict__ lps_b, const float* __restrict__ lpd_w,
                const float* __restrict__ lpd_b, const float* __restrict__ lpf_w,
                const float* __restrict__ lpf_b, float* __restrict__ out) {
  int t = threadIdx.x, w = t >> 6, j = t & 63;
  int b = blockIdx.x * 4 + w;
  const float* hs = h + (size_t)assoc[src[b]] * 64;
  const float* hd = h + (size_t)assoc[dst[b]] * 64;
  const float* hn = h + (size_t)assoc[neg[b]] * 64;
  float vs = lps_b[j], vd = lpd_b[j], vn = lpd_b[j];
  for (int k = 0; k < 64; k++) {
    float ws_ = lps_w[k * 64 + j];
    float wd_ = lpd_w[k * 64 + j];
    vs += hs[k] * ws_;
    vd += hd[k] * wd_;
    vn += hn[k] * wd_;
  }
  float fw = lpf_w[j];
  float hp = fmaxf(vs + vd, 0.f) * fw;
  float hq = fmaxf(vs + vn, 0.f) * fw;
  #pragma unroll
  for (int m = 1; m < 64; m <<= 1) {
    hp += __shfl_xor(hp, m, 64);
    hq += __shfl_xor(hq, m, 64);
  }
  if (j == 0) {
    out[b] = hp + lpf_b[0];
    out[NBATCH + b] = hq + lpf_b[0];
  }
}

extern "C" void kernel_launch(void* const* d_in, const int* in_sizes, int n_in,
                              void* d_out, int out_size, void* d_ws, size_t ws_size,
                              hipStream_t stream) {
  if (n_in < 30) return;
  const float* memory      = (const float*)d_in[0];
  const float* pos_memory  = (const float*)d_in[1];
  const float* last_update = (const float*)d_in[2];
  const int*   n_id        = (const int*)d_in[3];
  const int*   edge_index  = (const int*)d_in[4];
  const float* edge_t      = (const float*)d_in[5];
  const float* edge_msg    = (const float*)d_in[6];
  const int*   src         = (const int*)d_in[7];
  const int*   dst         = (const int*)d_in[8];
  const int*   neg_dst     = (const int*)d_in[9];
  const float* time_w      = (const float*)d_in[10];
  const float* time_b      = (const float*)d_in[11];
  const float* Wq = (const float*)d_in[12]; const float* bq = (const float*)d_in[13];
  const float* Wk = (const float*)d_in[14]; const float* bk = (const float*)d_in[15];
  const float* Wv = (const float*)d_in[16]; const float* bv = (const float*)d_in[17];
  const float* We = (const float*)d_in[18]; const float* be = (const float*)d_in[19];
  const float* Wskip = (const float*)d_in[20]; const float* bskip = (const float*)d_in[21];
  const float* mlp_w = (const float*)d_in[22]; const float* mlp_b = (const float*)d_in[23];
  const float* lps_w = (const float*)d_in[24]; const float* lps_b = (const float*)d_in[25];
  const float* lpd_w = (const float*)d_in[26]; const float* lpd_b = (const float*)d_in[27];
  const float* lpf_w = (const float*)d_in[28]; const float* lpf_b = (const float*)d_in[29];
  float* out = (float*)d_out;

  char* ws = (char*)d_ws;
  size_t off = 0;
  auto alloc = [&](size_t bytes) -> void* {
    void* p = ws + off;
    off += (bytes + 255) & ~(size_t)255;
    return p;
  };
  int*   assoc   = (int*)alloc((size_t)NNODES * 4);
  unsigned short* Wt  = (unsigned short*)alloc((size_t)768 * 256 * 2);
  float* bias    = (float*)alloc(768 * 4);
  unsigned short* W2t = (unsigned short*)alloc((size_t)64 * 512 * 2);
  float* bem     = (float*)alloc(128 * 4);
  float* rel_t   = (float*)alloc((size_t)NEDGE * 4);
  unsigned short* anodes  = (unsigned short*)alloc((size_t)NSUB * 256 * 2);
  unsigned short* nodeout = (unsigned short*)alloc((size_t)NSUB * 768 * 2);
  unsigned short* aggbuf  = (unsigned short*)alloc((size_t)NSUB * 512 * 2);
  float* salph   = (float*)alloc((size_t)NSUB * 2 * 4);
  int*   deg     = (int*)alloc((size_t)NSUB * 4);
  int*   offs    = (int*)alloc((size_t)(NSUB + 1) * 4);
  int*   cursor  = (int*)alloc((size_t)(NSUB + 1) * 4);
  int*   excl    = (int*)alloc((size_t)NSUB * 4);
  int*   btot    = (int*)alloc(64 * 4);
  uint4* csrmeta = (uint4*)alloc((size_t)NEDGE * 16);
  unsigned int* msgb = (unsigned int*)alloc((size_t)NEDGE * 64 * 2);
  float* hbuf    = (float*)alloc((size_t)NSUB * 64 * 4);

  if (ws_size < off) {
    k_sentinel<<<1, 1, 0, stream>>>(out);
    return;
  }

  (void)hipMemsetAsync(deg, 0, (size_t)NSUB * 4, stream);
  k_packAll<<<898, 256, 0, stream>>>(Wq, bq, Wk, bk, Wv, bv, Wskip, bskip, We, mlp_w, be,
                                     Wt, bias, W2t, bem);
  k_packA<<<NSUB * 32 / 256, 256, 0, stream>>>(memory, pos_memory, n_id, anodes, assoc);
  k_msgb<<<NEDGE * 32 / 256, 256, 0, stream>>>(edge_msg, msgb, edge_index, n_id,
                                               last_update, edge_t, rel_t, deg);
  k_scan1<<<NSUB / 1024, 1024, 0, stream>>>(deg, excl, btot);
  k_scan3<<<NSUB / 1024, 1024, 0, stream>>>(excl, btot, offs, cursor);
  k_scatter<<<NEDGE / 256, 256, 0, stream>>>(edge_index, rel_t, cursor, csrmeta);
  k_gemm_node<<<dim3(NSUB / 256, 6), 256, 0, stream>>>(anodes, Wt, bias, nodeout);
  k_edge<<<NSUB / 16, 256, 0, stream>>>(nodeout, (const unsigned short*)msgb, time_w, time_b,
                                        be, offs, csrmeta, aggbuf, salph);
  k_gemm_final<<<NSUB / 128, 128, 0, stream>>>(aggbuf, W2t, salph, bem, mlp_b, hbuf);
  k_linkpred<<<NBATCH / 4, 256, 0, stream>>>(hbuf, assoc, src, dst, neg_dst,
                                             lps_w, lps_b, lpd_w, lpd_b, lpf_w, lpf_b, out);
}